// Round 5
// baseline (657.813 us; speedup 1.0000x reference)
//
#include <hip/hip_runtime.h>
#include <math.h>

#define DEPTHL 4
#define HEADS 8
#define DH 64
#define DIM 512
#define BATCH 4
#define SEQ 512
#define ROWS (BATCH*SEQ)
#define SCALE 0.125f
#define LNEPS 1e-5f

typedef __attribute__((ext_vector_type(8))) short bfrag;   // 8 bf16 (4 VGPR)
typedef __attribute__((ext_vector_type(4))) float ffrag;   // 4 f32 acc
#define MFMA(a,b,c) __builtin_amdgcn_mfma_f32_16x16x32_bf16(a, b, c, 0, 0, 0)

__device__ __forceinline__ unsigned short f2bf(float f) {
    unsigned int u = __float_as_uint(f);
    u += 0x7fffu + ((u >> 16) & 1u);          // round-to-nearest-even
    return (unsigned short)(u >> 16);
}
__device__ __forceinline__ float bf2f(unsigned short b) {
    return __uint_as_float(((unsigned int)b) << 16);
}

// ---------------- weight fp32 -> bf16 (one layer: 6 x DIM*DIM) ----------------
__global__ __launch_bounds__(256) void convw(
    const float* __restrict__ s0, const float* __restrict__ s1,
    const float* __restrict__ s2, const float* __restrict__ s3,
    const float* __restrict__ s4, const float* __restrict__ s5,
    unsigned short* __restrict__ dst)
{
    int gid = blockIdx.x * 256 + threadIdx.x;
    int idx = gid * 4;
    int seg = idx >> 18;                 // DIM*DIM = 262144 per segment
    int off = idx & 262143;
    const float* s = seg == 0 ? s0 : seg == 1 ? s1 : seg == 2 ? s2 :
                     seg == 3 ? s3 : seg == 4 ? s4 : s5;
    float4 v = *(const float4*)(s + off);
    unsigned long long p = (unsigned long long)f2bf(v.x)
        | ((unsigned long long)f2bf(v.y) << 16)
        | ((unsigned long long)f2bf(v.z) << 32)
        | ((unsigned long long)f2bf(v.w) << 48);
    *(unsigned long long*)(dst + idx) = p;
}

// ---------------- block reduction helper ----------------
__device__ __forceinline__ void blk_sum4(float& a, float& b, float& c, float& d) {
    __shared__ float s[16];
    #pragma unroll
    for (int o = 32; o; o >>= 1) {
        a += __shfl_xor(a, o); b += __shfl_xor(b, o);
        c += __shfl_xor(c, o); d += __shfl_xor(d, o);
    }
    int w = threadIdx.x >> 6;
    if ((threadIdx.x & 63) == 0) { s[w*4+0]=a; s[w*4+1]=b; s[w*4+2]=c; s[w*4+3]=d; }
    __syncthreads();
    a = s[0]+s[4]+s[8]+s[12];
    b = s[1]+s[5]+s[9]+s[13];
    c = s[2]+s[6]+s[10]+s[14];
    d = s[3]+s[7]+s[11]+s[15];
    __syncthreads();
}

// ---------------- complex LayerNorm (fp32 in, bf16 out) ----------------
__global__ __launch_bounds__(256) void ln_kernel(
    const float* __restrict__ xr, const float* __restrict__ xi,
    const float* __restrict__ gr, const float* __restrict__ br,
    const float* __restrict__ gi, const float* __restrict__ bi,
    unsigned short* __restrict__ outr, unsigned short* __restrict__ outi)
{
    int row = blockIdx.x, t = threadIdx.x;
    float2 vr = ((const float2*)(xr + (size_t)row*DIM))[t];
    float2 vi = ((const float2*)(xi + (size_t)row*DIM))[t];
    float sr = vr.x+vr.y, qr = vr.x*vr.x+vr.y*vr.y;
    float si = vi.x+vi.y, qi = vi.x*vi.x+vi.y*vi.y;
    blk_sum4(sr, qr, si, qi);
    float mr = sr*(1.f/DIM), mi_ = si*(1.f/DIM);
    float rr = 1.f/sqrtf(qr*(1.f/DIM)-mr*mr+LNEPS);
    float ri = 1.f/sqrtf(qi*(1.f/DIM)-mi_*mi_+LNEPS);
    float2 g2r = ((const float2*)gr)[t], b2r = ((const float2*)br)[t];
    float2 g2i = ((const float2*)gi)[t], b2i = ((const float2*)bi)[t];
    float o0 = (vr.x-mr)*rr*g2r.x + b2r.x;
    float o1 = (vr.y-mr)*rr*g2r.y + b2r.y;
    float o2 = (vi.x-mi_)*ri*g2i.x + b2i.x;
    float o3 = (vi.y-mi_)*ri*g2i.y + b2i.y;
    unsigned int pr = (unsigned int)f2bf(o0) | ((unsigned int)f2bf(o1) << 16);
    unsigned int pi = (unsigned int)f2bf(o2) | ((unsigned int)f2bf(o3) << 16);
    ((unsigned int*)(outr + (size_t)row*DIM))[t] = pr;
    ((unsigned int*)(outi + (size_t)row*DIM))[t] = pi;
}

// ---------------- bf16 MFMA complex GEMM: out[r,e] = sum_k A[r,k]*W[e,k] ----------------
// grid (64, 8), block 256 = 4 waves (2x2), block tile 32(M)x64(N), wave 16x32.
// Register-pipelined k-loop (prefetch next 32-k fragment set during MFMAs).
template<int MODE>
__global__ __launch_bounds__(256, 4) void cgemm_mfma(
    const unsigned short* __restrict__ Ar, const unsigned short* __restrict__ Ai,
    const unsigned short* __restrict__ Wr, const unsigned short* __restrict__ Wi,
    unsigned short* __restrict__ Obr, unsigned short* __restrict__ Obi,
    float* __restrict__ Ofr, float* __restrict__ Ofi,
    const float* __restrict__ biasR, const float* __restrict__ biasI,
    const float* __restrict__ stepp, const float* __restrict__ lamb, int layer)
{
    int tid = threadIdx.x;
    int lane = tid & 63;
    int w = tid >> 6, wr = w >> 1, wc = w & 1;
    int lrow = lane & 15, lg = lane >> 4;
    int bm = blockIdx.x, bn = blockIdx.y;

    const unsigned short* pAr = Ar + (size_t)(bm*32 + wr*16 + lrow)*DIM + lg*8;
    const unsigned short* pAi = Ai + (size_t)(bm*32 + wr*16 + lrow)*DIM + lg*8;
    const unsigned short* pBr[2]; const unsigned short* pBi[2];
    #pragma unroll
    for (int nt = 0; nt < 2; ++nt) {
        int brow = bn*64 + wc*32 + nt*16 + lrow;
        pBr[nt] = Wr + (size_t)brow*DIM + lg*8;
        pBi[nt] = Wi + (size_t)brow*DIM + lg*8;
    }
    ffrag acc1[2], acc2[2], acci[2];
    #pragma unroll
    for (int nt = 0; nt < 2; ++nt) {
        acc1[nt] = (ffrag){0.f,0.f,0.f,0.f};
        acc2[nt] = (ffrag){0.f,0.f,0.f,0.f};
        acci[nt] = (ffrag){0.f,0.f,0.f,0.f};
    }

    bfrag a_r = *(const bfrag*)(pAr);
    bfrag a_i = *(const bfrag*)(pAi);
    bfrag b_r0 = *(const bfrag*)(pBr[0]), b_r1 = *(const bfrag*)(pBr[1]);
    bfrag b_i0 = *(const bfrag*)(pBi[0]), b_i1 = *(const bfrag*)(pBi[1]);

    #pragma unroll 2
    for (int k0 = 0; k0 < DIM - 32; k0 += 32) {
        bfrag na_r = *(const bfrag*)(pAr + k0 + 32);
        bfrag na_i = *(const bfrag*)(pAi + k0 + 32);
        bfrag nb_r0 = *(const bfrag*)(pBr[0] + k0 + 32);
        bfrag nb_r1 = *(const bfrag*)(pBr[1] + k0 + 32);
        bfrag nb_i0 = *(const bfrag*)(pBi[0] + k0 + 32);
        bfrag nb_i1 = *(const bfrag*)(pBi[1] + k0 + 32);
        acc1[0] = MFMA(a_r, b_r0, acc1[0]);
        acc2[0] = MFMA(a_i, b_i0, acc2[0]);
        acci[0] = MFMA(a_r, b_i0, acci[0]);
        acci[0] = MFMA(a_i, b_r0, acci[0]);
        acc1[1] = MFMA(a_r, b_r1, acc1[1]);
        acc2[1] = MFMA(a_i, b_i1, acc2[1]);
        acci[1] = MFMA(a_r, b_i1, acci[1]);
        acci[1] = MFMA(a_i, b_r1, acci[1]);
        a_r = na_r; a_i = na_i;
        b_r0 = nb_r0; b_r1 = nb_r1; b_i0 = nb_i0; b_i1 = nb_i1;
    }
    acc1[0] = MFMA(a_r, b_r0, acc1[0]);
    acc2[0] = MFMA(a_i, b_i0, acc2[0]);
    acci[0] = MFMA(a_r, b_i0, acci[0]);
    acci[0] = MFMA(a_i, b_r0, acci[0]);
    acc1[1] = MFMA(a_r, b_r1, acc1[1]);
    acc2[1] = MFMA(a_i, b_i1, acc2[1]);
    acci[1] = MFMA(a_r, b_i1, acci[1]);
    acci[1] = MFMA(a_i, b_r1, acci[1]);

    float ss = 0.f, sl = 0.f;
    if (MODE == 2) { ss = log1pf(expf(stepp[layer])); sl = ss * log1pf(expf(lamb[layer])); }

    #pragma unroll
    for (int nt = 0; nt < 2; ++nt) {
        int E = bn*64 + wc*32 + nt*16 + lrow;
        #pragma unroll
        for (int r = 0; r < 4; ++r) {
            int R = bm*32 + wr*16 + lg*4 + r;
            float re = acc1[nt][r] - acc2[nt][r];
            float im = acci[nt][r];
            if (MODE == 0) {
                int b = R >> 9, n = R & (SEQ-1);
                int h = E >> 6, d = E & 63;
                size_t off = (((size_t)(b*HEADS + h)*SEQ + n) << 6) + d;
                Obr[off] = f2bf(re);
                Obi[off] = f2bf(im);
            } else if (MODE == 1) {
                size_t off = (size_t)R*DIM + E;
                Ofr[off] = re + biasR[E] + Ofr[off];
                Ofi[off] = im + biasI[E] + Ofi[off];
            } else {
                size_t off = (size_t)R*DIM + E;
                float xnr_ = bf2f(Ar[off]), xni_ = bf2f(Ai[off]);
                Ofr[off] = fmaxf(xnr_ + ss*re - sl, 0.f);
                Ofi[off] = fmaxf(xni_ + ss*im, 0.f);
            }
        }
    }
}

// ---------------- MFMA flash attention, softmax on |z| phase preserved ----------------
// grid (32 bh, 32 qtiles of 16 rows). Block = 4 waves; wave w owns m-tiles
// {w*32 + rd*128} with PRIVATE flash state and PRIVATE LDS regions -> main loop
// is barrier-free. Final 4-way flash merge via LDS.
// z computed transposed (A=K, B=Q) so q = lane&15 -> per-lane flash state.
#define SVI(w_, ri, d, m) ((((w_)*2 + (ri))*64 + (d))*40 + (m))
#define SPI(w_, ri, q, m) (20480 + (((w_)*2 + (ri))*16 + (q))*40 + (m))

__global__ __launch_bounds__(256, 3) void attn_mfma(
    const unsigned short* __restrict__ whr, const unsigned short* __restrict__ whi,
    unsigned short* __restrict__ aor, unsigned short* __restrict__ aoi)
{
    __shared__ __align__(16) unsigned short pool[25856];
    float* sMS = (float*)(pool + 25600);     // [4][2][16]
    float* sAccR = (float*)pool;             // overlay (merge phase only): [64][16]
    float* sAccI = sAccR + 64*16;

    int tid = threadIdx.x, lane = tid & 63, w = tid >> 6;
    int lrow = lane & 15, lg = lane >> 4;
    int bh = blockIdx.x, qt = blockIdx.y;
    const unsigned short* baseR = whr + ((size_t)bh << 15);   // *512*64
    const unsigned short* baseI = whi + ((size_t)bh << 15);
    int q0 = qt*16;

    bfrag qfr[2], qfi[2];
    #pragma unroll
    for (int ks = 0; ks < 2; ++ks) {
        qfr[ks] = *(const bfrag*)(baseR + ((size_t)(q0 + lrow) << 6) + ks*32 + lg*8);
        qfi[ks] = *(const bfrag*)(baseI + ((size_t)(q0 + lrow) << 6) + ks*32 + lg*8);
    }
    float M = -1e30f, S = 0.f;
    ffrag o1[4], o2[4], o3[4];   // O^T accs: SumVrPr, SumViPi, Sum(VrPi+ViPr)
    #pragma unroll
    for (int dt = 0; dt < 4; ++dt) {
        o1[dt] = (ffrag){0.f,0.f,0.f,0.f};
        o2[dt] = (ffrag){0.f,0.f,0.f,0.f};
        o3[dt] = (ffrag){0.f,0.f,0.f,0.f};
    }
    const int sm = lane & 31;
    const int sdb = ((lane >> 5) & 1) * 8;

    #pragma unroll 1
    for (int rd = 0; rd < 4; ++rd) {
        int m0 = rd*128 + w*32;            // this wave's m-tile
        // stage V^T for own tile into private region (in-wave RAW/WAR via lgkmcnt)
        #pragma unroll
        for (int it = 0; it < 4; ++it) {
            int d0 = sdb + it*16;
            bfrag vr = *(const bfrag*)(baseR + ((size_t)(m0 + sm) << 6) + d0);
            bfrag vi = *(const bfrag*)(baseI + ((size_t)(m0 + sm) << 6) + d0);
            #pragma unroll
            for (int j = 0; j < 8; ++j) {
                pool[SVI(w, 0, d0 + j, sm)] = (unsigned short)vr[j];
                pool[SVI(w, 1, d0 + j, sm)] = (unsigned short)vi[j];
            }
        }
        // z^T[m][q] = sum_d K[m,d]*conj-combine Q[q,d]  (K frags from global/L2)
        ffrag zr[2], zp[2], zm_[2];
        #pragma unroll
        for (int t = 0; t < 2; ++t) {
            zr[t] = (ffrag){0.f,0.f,0.f,0.f};
            zp[t] = (ffrag){0.f,0.f,0.f,0.f};
            zm_[t] = (ffrag){0.f,0.f,0.f,0.f};
        }
        #pragma unroll
        for (int t = 0; t < 2; ++t)
        #pragma unroll
        for (int ks = 0; ks < 2; ++ks) {
            bfrag kr = *(const bfrag*)(baseR + ((size_t)(m0 + t*16 + lrow) << 6) + ks*32 + lg*8);
            bfrag ki = *(const bfrag*)(baseI + ((size_t)(m0 + t*16 + lrow) << 6) + ks*32 + lg*8);
            zr[t]  = MFMA(kr, qfr[ks], zr[t]);
            zr[t]  = MFMA(ki, qfi[ks], zr[t]);
            zp[t]  = MFMA(kr, qfi[ks], zp[t]);
            zm_[t] = MFMA(ki, qfr[ks], zm_[t]);
        }
        // online softmax on |z|; lane's q = lrow; its 8 m: m0 + t*16 + lg*4 + r
        float av[2][4], rv[2][4], iv[2][4];
        float pmax = -1e30f;
        #pragma unroll
        for (int t = 0; t < 2; ++t)
        #pragma unroll
        for (int r = 0; r < 4; ++r) {
            float zrv = zr[t][r] * SCALE;
            float ziv = (zp[t][r] - zm_[t][r]) * SCALE;
            float a = sqrtf(zrv*zrv + ziv*ziv);
            av[t][r] = a; rv[t][r] = zrv; iv[t][r] = ziv;
            pmax = fmaxf(pmax, a);
        }
        pmax = fmaxf(pmax, __shfl_xor(pmax, 16));
        pmax = fmaxf(pmax, __shfl_xor(pmax, 32));
        float Mnew = fmaxf(M, pmax);
        float f = expf(M - Mnew);
        M = Mnew;
        S *= f;
        #pragma unroll
        for (int dt = 0; dt < 4; ++dt) { o1[dt] *= f; o2[dt] *= f; o3[dt] *= f; }
        float ssum = 0.f;
        #pragma unroll
        for (int t = 0; t < 2; ++t) {
            float ur[4], ui[4];
            #pragma unroll
            for (int r = 0; r < 4; ++r) {
                float a = av[t][r];
                float ee = expf(a - M);
                ssum += ee;
                float inva = a > 0.f ? ee / a : 0.f;
                ur[r] = a > 0.f ? inva * rv[t][r] : ee;
                ui[r] = inva * iv[t][r];
            }
            uint2 wpr, wpi;
            wpr.x = (unsigned int)f2bf(ur[0]) | ((unsigned int)f2bf(ur[1]) << 16);
            wpr.y = (unsigned int)f2bf(ur[2]) | ((unsigned int)f2bf(ur[3]) << 16);
            wpi.x = (unsigned int)f2bf(ui[0]) | ((unsigned int)f2bf(ui[1]) << 16);
            wpi.y = (unsigned int)f2bf(ui[2]) | ((unsigned int)f2bf(ui[3]) << 16);
            *(uint2*)&pool[SPI(w, 0, lrow, t*16 + lg*4)] = wpr;
            *(uint2*)&pool[SPI(w, 1, lrow, t*16 + lg*4)] = wpi;
        }
        ssum += __shfl_xor(ssum, 16);
        ssum += __shfl_xor(ssum, 32);
        S += ssum;
        // PV: O^T[d][q] += V^T * P   (all reads from own private LDS regions)
        bfrag pr = *(const bfrag*)&pool[SPI(w, 0, lrow, lg*8)];
        bfrag pi = *(const bfrag*)&pool[SPI(w, 1, lrow, lg*8)];
        #pragma unroll
        for (int dt = 0; dt < 4; ++dt) {
            bfrag vr = *(const bfrag*)&pool[SVI(w, 0, dt*16 + lrow, lg*8)];
            bfrag vi = *(const bfrag*)&pool[SVI(w, 1, dt*16 + lrow, lg*8)];
            o1[dt] = MFMA(vr, pr, o1[dt]);
            o2[dt] = MFMA(vi, pi, o2[dt]);
            o3[dt] = MFMA(vr, pi, o3[dt]);
            o3[dt] = MFMA(vi, pr, o3[dt]);
        }
    }

    // ---- 4-way flash merge across waves ----
    if (lg == 0) { sMS[(w*2 + 0)*16 + lrow] = M; sMS[(w*2 + 1)*16 + lrow] = S; }
    __syncthreads();
    float Mf = -1e30f;
    #pragma unroll
    for (int w2 = 0; w2 < 4; ++w2) Mf = fmaxf(Mf, sMS[(w2*2 + 0)*16 + lrow]);
    float Sf = 0.f;
    #pragma unroll
    for (int w2 = 0; w2 < 4; ++w2)
        Sf += sMS[(w2*2 + 1)*16 + lrow] * expf(sMS[(w2*2 + 0)*16 + lrow] - Mf);
    float fac = expf(M - Mf) / Sf;

    #pragma unroll 1
    for (int ww = 0; ww < 4; ++ww) {
        if (w == ww) {
            #pragma unroll
            for (int dt = 0; dt < 4; ++dt)
            #pragma unroll
            for (int r = 0; r < 4; ++r) {
                int d = dt*16 + lg*4 + r;
                float vR = (o1[dt][r] - o2[dt][r]) * fac;
                float vI = o3[dt][r] * fac;
                if (ww == 0) { sAccR[d*16 + lrow] = vR; sAccI[d*16 + lrow] = vI; }
                else         { sAccR[d*16 + lrow] += vR; sAccI[d*16 + lrow] += vI; }
            }
        }
        __syncthreads();
    }
    // coalesced bf16 write-out: thread -> (q = tid>>4, d0 = (tid&15)*4)
    {
        int q = tid >> 4, d0 = (tid & 15) * 4;
        int b = bh >> 3, h = bh & 7;
        float r0 = sAccR[(d0+0)*16 + q], r1 = sAccR[(d0+1)*16 + q];
        float r2 = sAccR[(d0+2)*16 + q], r3 = sAccR[(d0+3)*16 + q];
        float i0 = sAccI[(d0+0)*16 + q], i1 = sAccI[(d0+1)*16 + q];
        float i2 = sAccI[(d0+2)*16 + q], i3 = sAccI[(d0+3)*16 + q];
        uint2 pr, pi;
        pr.x = (unsigned int)f2bf(r0) | ((unsigned int)f2bf(r1) << 16);
        pr.y = (unsigned int)f2bf(r2) | ((unsigned int)f2bf(r3) << 16);
        pi.x = (unsigned int)f2bf(i0) | ((unsigned int)f2bf(i1) << 16);
        pi.y = (unsigned int)f2bf(i2) | ((unsigned int)f2bf(i3) << 16);
        size_t off = (((size_t)(bh >> 3)*SEQ + qt*16 + q) << 9) + (bh & 7)*64 + d0;
        *(uint2*)(aor + off) = pr;
        *(uint2*)(aoi + off) = pi;
    }
}

// ---------------- launch ----------------
extern "C" void kernel_launch(void* const* d_in, const int* in_sizes, int n_in,
                              void* d_out, int out_size, void* d_ws, size_t ws_size,
                              hipStream_t stream)
{
    const float* x_real  = (const float*)d_in[0];
    const float* x_imag  = (const float*)d_in[1];
    const float* ln1_g_r = (const float*)d_in[2];
    const float* ln1_b_r = (const float*)d_in[3];
    const float* ln1_g_i = (const float*)d_in[4];
    const float* ln1_b_i = (const float*)d_in[5];
    const float* ln2_g_r = (const float*)d_in[6];
    const float* ln2_b_r = (const float*)d_in[7];
    const float* ln2_g_i = (const float*)d_in[8];
    const float* ln2_b_i = (const float*)d_in[9];
    const float* qkv_w_r = (const float*)d_in[10];
    const float* qkv_w_i = (const float*)d_in[11];
    const float* out_w_r = (const float*)d_in[12];
    const float* out_w_i = (const float*)d_in[13];
    const float* out_b_r = (const float*)d_in[14];
    const float* out_b_i = (const float*)d_in[15];
    const float* ff_w_r  = (const float*)d_in[16];
    const float* ff_w_i  = (const float*)d_in[17];
    const float* stepp   = (const float*)d_in[18];
    const float* lamb    = (const float*)d_in[19];

    const size_t SZ = (size_t)ROWS * DIM;       // 1M elems
    const size_t WSEG = (size_t)DIM * DIM;      // 256K elems
    float* xr = (float*)d_ws;
    float* xi = xr + SZ;
    unsigned short* xnr = (unsigned short*)(xi + SZ);
    unsigned short* xni = xnr + SZ;
    unsigned short* whr = xni + SZ;
    unsigned short* whi = whr + SZ;
    unsigned short* aor = whi + SZ;
    unsigned short* aoi = aor + SZ;
    unsigned short* wb  = aoi + SZ;             // 6*WSEG bf16 (one layer)

    float* outR = (float*)d_out;
    float* outI = outR + SZ;

    hipMemcpyAsync(xr, x_real, SZ*sizeof(float), hipMemcpyDeviceToDevice, stream);
    hipMemcpyAsync(xi, x_imag, SZ*sizeof(float), hipMemcpyDeviceToDevice, stream);

    for (int l = 0; l < DEPTHL; ++l) {
        const size_t WO = (size_t)l * WSEG;
        convw<<<1536, 256, 0, stream>>>(qkv_w_r + WO, qkv_w_i + WO, out_w_r + WO,
                                        out_w_i + WO, ff_w_r + WO, ff_w_i + WO, wb);
        ln_kernel<<<ROWS, 256, 0, stream>>>(xr, xi,
            ln1_g_r + l*DIM, ln1_b_r + l*DIM, ln1_g_i + l*DIM, ln1_b_i + l*DIM, xnr, xni);
        cgemm_mfma<0><<<dim3(64, 8), 256, 0, stream>>>(xnr, xni, wb, wb + WSEG,
            whr, whi, nullptr, nullptr, nullptr, nullptr, nullptr, nullptr, l);
        attn_mfma<<<dim3(32, 32), 256, 0, stream>>>(whr, whi, aor, aoi);
        cgemm_mfma<1><<<dim3(64, 8), 256, 0, stream>>>(aor, aoi, wb + 2*WSEG, wb + 3*WSEG,
            nullptr, nullptr, xr, xi, out_b_r + l*DIM, out_b_i + l*DIM, nullptr, nullptr, l);
        ln_kernel<<<ROWS, 256, 0, stream>>>(xr, xi,
            ln2_g_r + l*DIM, ln2_b_r + l*DIM, ln2_g_i + l*DIM, ln2_b_i + l*DIM, xnr, xni);
        float* dstR = (l == DEPTHL-1) ? outR : xr;
        float* dstI = (l == DEPTHL-1) ? outI : xi;
        cgemm_mfma<2><<<dim3(64, 8), 256, 0, stream>>>(xnr, xni, wb + 4*WSEG, wb + 5*WSEG,
            nullptr, nullptr, dstR, dstI, nullptr, nullptr, stepp, lamb, l);
    }
}

// Round 6
// 636.139 us; speedup vs baseline: 1.0341x; 1.0341x over previous
//
#include <hip/hip_runtime.h>
#include <math.h>

#define DEPTHL 4
#define HEADS 8
#define DH 64
#define DIM 512
#define BATCH 4
#define SEQ 512
#define ROWS (BATCH*SEQ)
#define SCALE 0.125f
#define LNEPS 1e-5f

typedef __attribute__((ext_vector_type(8))) short bfrag;   // 8 bf16 (4 VGPR)
typedef __attribute__((ext_vector_type(4))) float ffrag;   // 4 f32 acc
#define MFMA(a,b,c) __builtin_amdgcn_mfma_f32_16x16x32_bf16(a, b, c, 0, 0, 0)

__device__ __forceinline__ unsigned short f2bf(float f) {
    unsigned int u = __float_as_uint(f);
    u += 0x7fffu + ((u >> 16) & 1u);          // round-to-nearest-even
    return (unsigned short)(u >> 16);
}
__device__ __forceinline__ float bf2f(unsigned short b) {
    return __uint_as_float(((unsigned int)b) << 16);
}

// ---------------- weight fp32 -> bf16 (one layer: 6 x DIM*DIM) ----------------
__global__ __launch_bounds__(256) void convw(
    const float* __restrict__ s0, const float* __restrict__ s1,
    const float* __restrict__ s2, const float* __restrict__ s3,
    const float* __restrict__ s4, const float* __restrict__ s5,
    unsigned short* __restrict__ dst)
{
    int gid = blockIdx.x * 256 + threadIdx.x;
    int idx = gid * 4;
    int seg = idx >> 18;                 // DIM*DIM = 262144 per segment
    int off = idx & 262143;
    const float* s = seg == 0 ? s0 : seg == 1 ? s1 : seg == 2 ? s2 :
                     seg == 3 ? s3 : seg == 4 ? s4 : s5;
    float4 v = *(const float4*)(s + off);
    unsigned long long p = (unsigned long long)f2bf(v.x)
        | ((unsigned long long)f2bf(v.y) << 16)
        | ((unsigned long long)f2bf(v.z) << 32)
        | ((unsigned long long)f2bf(v.w) << 48);
    *(unsigned long long*)(dst + idx) = p;
}

// ---------------- block reduction helper ----------------
__device__ __forceinline__ void blk_sum4(float& a, float& b, float& c, float& d) {
    __shared__ float s[16];
    #pragma unroll
    for (int o = 32; o; o >>= 1) {
        a += __shfl_xor(a, o); b += __shfl_xor(b, o);
        c += __shfl_xor(c, o); d += __shfl_xor(d, o);
    }
    int w = threadIdx.x >> 6;
    if ((threadIdx.x & 63) == 0) { s[w*4+0]=a; s[w*4+1]=b; s[w*4+2]=c; s[w*4+3]=d; }
    __syncthreads();
    a = s[0]+s[4]+s[8]+s[12];
    b = s[1]+s[5]+s[9]+s[13];
    c = s[2]+s[6]+s[10]+s[14];
    d = s[3]+s[7]+s[11]+s[15];
    __syncthreads();
}

// ---------------- complex LayerNorm (fp32 in, bf16 out) ----------------
__global__ __launch_bounds__(256) void ln_kernel(
    const float* __restrict__ xr, const float* __restrict__ xi,
    const float* __restrict__ gr, const float* __restrict__ br,
    const float* __restrict__ gi, const float* __restrict__ bi,
    unsigned short* __restrict__ outr, unsigned short* __restrict__ outi)
{
    int row = blockIdx.x, t = threadIdx.x;
    float2 vr = ((const float2*)(xr + (size_t)row*DIM))[t];
    float2 vi = ((const float2*)(xi + (size_t)row*DIM))[t];
    float sr = vr.x+vr.y, qr = vr.x*vr.x+vr.y*vr.y;
    float si = vi.x+vi.y, qi = vi.x*vi.x+vi.y*vi.y;
    blk_sum4(sr, qr, si, qi);
    float mr = sr*(1.f/DIM), mi_ = si*(1.f/DIM);
    float rr = 1.f/sqrtf(qr*(1.f/DIM)-mr*mr+LNEPS);
    float ri = 1.f/sqrtf(qi*(1.f/DIM)-mi_*mi_+LNEPS);
    float2 g2r = ((const float2*)gr)[t], b2r = ((const float2*)br)[t];
    float2 g2i = ((const float2*)gi)[t], b2i = ((const float2*)bi)[t];
    float o0 = (vr.x-mr)*rr*g2r.x + b2r.x;
    float o1 = (vr.y-mr)*rr*g2r.y + b2r.y;
    float o2 = (vi.x-mi_)*ri*g2i.x + b2i.x;
    float o3 = (vi.y-mi_)*ri*g2i.y + b2i.y;
    unsigned int pr = (unsigned int)f2bf(o0) | ((unsigned int)f2bf(o1) << 16);
    unsigned int pi = (unsigned int)f2bf(o2) | ((unsigned int)f2bf(o3) << 16);
    ((unsigned int*)(outr + (size_t)row*DIM))[t] = pr;
    ((unsigned int*)(outi + (size_t)row*DIM))[t] = pi;
}

// ---------------- bf16 MFMA complex GEMM: out[r,e] = sum_k A[r,k]*W[e,k] ----------------
// grid (64, 8), block 256 = 4 waves (2x2), block tile 32(M)x64(N), wave 16x32.
// k-step 64: 12 frag loads in flight, unroll-2 register double buffering.
template<int MODE>
__global__ __launch_bounds__(256, 2) void cgemm_mfma(
    const unsigned short* __restrict__ Ar, const unsigned short* __restrict__ Ai,
    const unsigned short* __restrict__ Wr, const unsigned short* __restrict__ Wi,
    unsigned short* __restrict__ Obr, unsigned short* __restrict__ Obi,
    float* __restrict__ Ofr, float* __restrict__ Ofi,
    const float* __restrict__ biasR, const float* __restrict__ biasI,
    const float* __restrict__ stepp, const float* __restrict__ lamb, int layer)
{
    int tid = threadIdx.x;
    int lane = tid & 63;
    int w = tid >> 6, wr = w >> 1, wc = w & 1;
    int lrow = lane & 15, lg = lane >> 4;
    int bm = blockIdx.x, bn = blockIdx.y;

    const unsigned short* pAr = Ar + (size_t)(bm*32 + wr*16 + lrow)*DIM + lg*8;
    const unsigned short* pAi = Ai + (size_t)(bm*32 + wr*16 + lrow)*DIM + lg*8;
    const unsigned short* pBr0 = Wr + (size_t)(bn*64 + wc*32 + lrow)*DIM + lg*8;
    const unsigned short* pBi0 = Wi + (size_t)(bn*64 + wc*32 + lrow)*DIM + lg*8;
    const unsigned short* pBr1 = pBr0 + (size_t)16*DIM;
    const unsigned short* pBi1 = pBi0 + (size_t)16*DIM;

    ffrag acc1[2], acc2[2], acci[2];
    #pragma unroll
    for (int nt = 0; nt < 2; ++nt) {
        acc1[nt] = (ffrag){0.f,0.f,0.f,0.f};
        acc2[nt] = (ffrag){0.f,0.f,0.f,0.f};
        acci[nt] = (ffrag){0.f,0.f,0.f,0.f};
    }

    bfrag ar0  = *(const bfrag*)(pAr),       ar1  = *(const bfrag*)(pAr + 32);
    bfrag ai0  = *(const bfrag*)(pAi),       ai1  = *(const bfrag*)(pAi + 32);
    bfrag br00 = *(const bfrag*)(pBr0),      br01 = *(const bfrag*)(pBr0 + 32);
    bfrag br10 = *(const bfrag*)(pBr1),      br11 = *(const bfrag*)(pBr1 + 32);
    bfrag bi00 = *(const bfrag*)(pBi0),      bi01 = *(const bfrag*)(pBi0 + 32);
    bfrag bi10 = *(const bfrag*)(pBi1),      bi11 = *(const bfrag*)(pBi1 + 32);

    #pragma unroll 2
    for (int k0 = 0; k0 < DIM - 64; k0 += 64) {
        bfrag nar0  = *(const bfrag*)(pAr  + k0 + 64), nar1  = *(const bfrag*)(pAr  + k0 + 96);
        bfrag nai0  = *(const bfrag*)(pAi  + k0 + 64), nai1  = *(const bfrag*)(pAi  + k0 + 96);
        bfrag nbr00 = *(const bfrag*)(pBr0 + k0 + 64), nbr01 = *(const bfrag*)(pBr0 + k0 + 96);
        bfrag nbr10 = *(const bfrag*)(pBr1 + k0 + 64), nbr11 = *(const bfrag*)(pBr1 + k0 + 96);
        bfrag nbi00 = *(const bfrag*)(pBi0 + k0 + 64), nbi01 = *(const bfrag*)(pBi0 + k0 + 96);
        bfrag nbi10 = *(const bfrag*)(pBi1 + k0 + 64), nbi11 = *(const bfrag*)(pBi1 + k0 + 96);

        acc1[0] = MFMA(ar0, br00, acc1[0]);  acc1[0] = MFMA(ar1, br01, acc1[0]);
        acc2[0] = MFMA(ai0, bi00, acc2[0]);  acc2[0] = MFMA(ai1, bi01, acc2[0]);
        acci[0] = MFMA(ar0, bi00, acci[0]);  acci[0] = MFMA(ai0, br00, acci[0]);
        acci[0] = MFMA(ar1, bi01, acci[0]);  acci[0] = MFMA(ai1, br01, acci[0]);
        acc1[1] = MFMA(ar0, br10, acc1[1]);  acc1[1] = MFMA(ar1, br11, acc1[1]);
        acc2[1] = MFMA(ai0, bi10, acc2[1]);  acc2[1] = MFMA(ai1, bi11, acc2[1]);
        acci[1] = MFMA(ar0, bi10, acci[1]);  acci[1] = MFMA(ai0, br10, acci[1]);
        acci[1] = MFMA(ar1, bi11, acci[1]);  acci[1] = MFMA(ai1, br11, acci[1]);

        ar0 = nar0; ar1 = nar1; ai0 = nai0; ai1 = nai1;
        br00 = nbr00; br01 = nbr01; br10 = nbr10; br11 = nbr11;
        bi00 = nbi00; bi01 = nbi01; bi10 = nbi10; bi11 = nbi11;
    }
    acc1[0] = MFMA(ar0, br00, acc1[0]);  acc1[0] = MFMA(ar1, br01, acc1[0]);
    acc2[0] = MFMA(ai0, bi00, acc2[0]);  acc2[0] = MFMA(ai1, bi01, acc2[0]);
    acci[0] = MFMA(ar0, bi00, acci[0]);  acci[0] = MFMA(ai0, br00, acci[0]);
    acci[0] = MFMA(ar1, bi01, acci[0]);  acci[0] = MFMA(ai1, br01, acci[0]);
    acc1[1] = MFMA(ar0, br10, acc1[1]);  acc1[1] = MFMA(ar1, br11, acc1[1]);
    acc2[1] = MFMA(ai0, bi10, acc2[1]);  acc2[1] = MFMA(ai1, bi11, acc2[1]);
    acci[1] = MFMA(ar0, bi10, acci[1]);  acci[1] = MFMA(ai0, br10, acci[1]);
    acci[1] = MFMA(ar1, bi11, acci[1]);  acci[1] = MFMA(ai1, br11, acci[1]);

    float ss = 0.f, sl = 0.f;
    if (MODE == 2) { ss = log1pf(expf(stepp[layer])); sl = ss * log1pf(expf(lamb[layer])); }

    #pragma unroll
    for (int nt = 0; nt < 2; ++nt) {
        int E = bn*64 + wc*32 + nt*16 + lrow;
        #pragma unroll
        for (int r = 0; r < 4; ++r) {
            int R = bm*32 + wr*16 + lg*4 + r;
            float re = acc1[nt][r] - acc2[nt][r];
            float im = acci[nt][r];
            if (MODE == 0) {
                int b = R >> 9, n = R & (SEQ-1);
                int h = E >> 6, d = E & 63;
                size_t off = (((size_t)(b*HEADS + h)*SEQ + n) << 6) + d;
                Obr[off] = f2bf(re);
                Obi[off] = f2bf(im);
            } else if (MODE == 1) {
                size_t off = (size_t)R*DIM + E;
                Ofr[off] = re + biasR[E] + Ofr[off];
                Ofi[off] = im + biasI[E] + Ofi[off];
            } else {
                size_t off = (size_t)R*DIM + E;
                float xnr_ = bf2f(Ar[off]), xni_ = bf2f(Ai[off]);
                Ofr[off] = fmaxf(xnr_ + ss*re - sl, 0.f);
                Ofi[off] = fmaxf(xni_ + ss*im, 0.f);
            }
        }
    }
}

// ---------------- MFMA flash attention, softmax on |z| phase preserved ----------------
// grid (32 bh, 8 qtiles of 64). Block = 512 thr = 8 waves.
// In-block m-split: group g = w>>2 owns m in [g*256, g*256+256) (8 iters of 32);
// wave qw = w&3 owns q rows [qt*64+qw*16, +16). Group-private V LDS, wave-private
// P LDS, per-lane flash state; 2-way flash merge at the end. K/V traffic per block
// identical to the 64-row-tile version (each m staged exactly once per block).
#define SVI(g_, ri, d, m) ((((g_)*2 + (ri))*64 + (d))*40 + (m))
#define SPI(w_, ri, q, m) (10240 + (((w_)*2 + (ri))*16 + (q))*40 + (m))

__global__ __launch_bounds__(512, 1) void attn_mfma(
    const unsigned short* __restrict__ whr, const unsigned short* __restrict__ whi,
    unsigned short* __restrict__ aor, unsigned short* __restrict__ aoi)
{
    __shared__ __align__(16) unsigned short pool[20992];
    float* sMS  = (float*)(pool + 20480);   // [8 waves][2][16 q]
    float* sAccR = (float*)pool;            // overlay (merge only): [4 qw][64 d][16 q]
    float* sAccI = sAccR + 4096;

    int tid = threadIdx.x, lane = tid & 63, w = tid >> 6;
    int qw = w & 3, g = w >> 2;
    int lrow = lane & 15, lg = lane >> 4;
    int bh = blockIdx.x, qt = blockIdx.y;
    const unsigned short* baseR = whr + ((size_t)bh << 15);   // *512*64
    const unsigned short* baseI = whi + ((size_t)bh << 15);
    int q0 = qt*64 + qw*16;

    bfrag qfr[2], qfi[2];
    #pragma unroll
    for (int ks = 0; ks < 2; ++ks) {
        qfr[ks] = *(const bfrag*)(baseR + ((size_t)(q0 + lrow) << 6) + ks*32 + lg*8);
        qfi[ks] = *(const bfrag*)(baseI + ((size_t)(q0 + lrow) << 6) + ks*32 + lg*8);
    }
    float M = -1e30f, S = 0.f;
    ffrag o1[4], o2[4], o3[4];   // O^T accs: SumVrPr, SumViPi, Sum(VrPi+ViPr)
    #pragma unroll
    for (int dt = 0; dt < 4; ++dt) {
        o1[dt] = (ffrag){0.f,0.f,0.f,0.f};
        o2[dt] = (ffrag){0.f,0.f,0.f,0.f};
        o3[dt] = (ffrag){0.f,0.f,0.f,0.f};
    }
    int t8 = tid & 255;
    int sm = t8 & 31, sdb = (t8 >> 5) * 8;   // 256 thr cover 32 m x 64 d

    #pragma unroll 1
    for (int it = 0; it < 8; ++it) {
        int m0 = g*256 + it*32;
        __syncthreads();   // prev PV reads done before sV overwrite
        {   // stage V^T into group region (one shot: 32 m x 64 d per group)
            bfrag vr = *(const bfrag*)(baseR + ((size_t)(m0 + sm) << 6) + sdb);
            bfrag vi = *(const bfrag*)(baseI + ((size_t)(m0 + sm) << 6) + sdb);
            #pragma unroll
            for (int j = 0; j < 8; ++j) {
                pool[SVI(g, 0, sdb + j, sm)] = (unsigned short)vr[j];
                pool[SVI(g, 1, sdb + j, sm)] = (unsigned short)vi[j];
            }
        }
        // z^T[m][q] = sum_d K[m,d]*conj-combine Q[q,d]  (K frags from global/L2)
        ffrag zr[2], zp[2], zm_[2];
        #pragma unroll
        for (int t = 0; t < 2; ++t) {
            zr[t] = (ffrag){0.f,0.f,0.f,0.f};
            zp[t] = (ffrag){0.f,0.f,0.f,0.f};
            zm_[t] = (ffrag){0.f,0.f,0.f,0.f};
        }
        #pragma unroll
        for (int t = 0; t < 2; ++t)
        #pragma unroll
        for (int ks = 0; ks < 2; ++ks) {
            bfrag kr = *(const bfrag*)(baseR + ((size_t)(m0 + t*16 + lrow) << 6) + ks*32 + lg*8);
            bfrag ki = *(const bfrag*)(baseI + ((size_t)(m0 + t*16 + lrow) << 6) + ks*32 + lg*8);
            zr[t]  = MFMA(kr, qfr[ks], zr[t]);
            zr[t]  = MFMA(ki, qfi[ks], zr[t]);
            zp[t]  = MFMA(kr, qfi[ks], zp[t]);
            zm_[t] = MFMA(ki, qfr[ks], zm_[t]);
        }
        // online softmax on |z|; lane's q = lrow; its 8 m: m0 + t*16 + lg*4 + r
        float av[2][4], rv[2][4], iv[2][4];
        float pmax = -1e30f;
        #pragma unroll
        for (int t = 0; t < 2; ++t)
        #pragma unroll
        for (int r = 0; r < 4; ++r) {
            float zrv = zr[t][r] * SCALE;
            float ziv = (zp[t][r] - zm_[t][r]) * SCALE;
            float a = sqrtf(zrv*zrv + ziv*ziv);
            av[t][r] = a; rv[t][r] = zrv; iv[t][r] = ziv;
            pmax = fmaxf(pmax, a);
        }
        pmax = fmaxf(pmax, __shfl_xor(pmax, 16));
        pmax = fmaxf(pmax, __shfl_xor(pmax, 32));
        float Mnew = fmaxf(M, pmax);
        float f = expf(M - Mnew);
        M = Mnew;
        S *= f;
        #pragma unroll
        for (int dt = 0; dt < 4; ++dt) { o1[dt] *= f; o2[dt] *= f; o3[dt] *= f; }
        float ssum = 0.f;
        #pragma unroll
        for (int t = 0; t < 2; ++t) {
            float ur[4], ui[4];
            #pragma unroll
            for (int r = 0; r < 4; ++r) {
                float a = av[t][r];
                float ee = expf(a - M);
                ssum += ee;
                float inva = a > 0.f ? ee / a : 0.f;
                ur[r] = a > 0.f ? inva * rv[t][r] : ee;
                ui[r] = inva * iv[t][r];
            }
            uint2 wpr, wpi;
            wpr.x = (unsigned int)f2bf(ur[0]) | ((unsigned int)f2bf(ur[1]) << 16);
            wpr.y = (unsigned int)f2bf(ur[2]) | ((unsigned int)f2bf(ur[3]) << 16);
            wpi.x = (unsigned int)f2bf(ui[0]) | ((unsigned int)f2bf(ui[1]) << 16);
            wpi.y = (unsigned int)f2bf(ui[2]) | ((unsigned int)f2bf(ui[3]) << 16);
            *(uint2*)&pool[SPI(w, 0, lrow, t*16 + lg*4)] = wpr;
            *(uint2*)&pool[SPI(w, 1, lrow, t*16 + lg*4)] = wpi;
        }
        ssum += __shfl_xor(ssum, 16);
        ssum += __shfl_xor(ssum, 32);
        S += ssum;
        __syncthreads();   // sV staged + sP written, visible to group/wave
        // PV: O^T[d][q] += V^T * P
        bfrag pr = *(const bfrag*)&pool[SPI(w, 0, lrow, lg*8)];
        bfrag pi = *(const bfrag*)&pool[SPI(w, 1, lrow, lg*8)];
        #pragma unroll
        for (int dt = 0; dt < 4; ++dt) {
            bfrag vr = *(const bfrag*)&pool[SVI(g, 0, dt*16 + lrow, lg*8)];
            bfrag vi = *(const bfrag*)&pool[SVI(g, 1, dt*16 + lrow, lg*8)];
            o1[dt] = MFMA(vr, pr, o1[dt]);
            o2[dt] = MFMA(vi, pi, o2[dt]);
            o3[dt] = MFMA(vr, pi, o3[dt]);
            o3[dt] = MFMA(vi, pr, o3[dt]);
        }
    }

    // ---- 2-way flash merge: wave w (g=0) with wave w^4 (g=1), same q rows ----
    if (lg == 0) { sMS[(w*2 + 0)*16 + lrow] = M; sMS[(w*2 + 1)*16 + lrow] = S; }
    __syncthreads();   // also guarantees all PV (sP/sV reads) complete before overlay
    int wp = w ^ 4;
    float Mp = sMS[(wp*2 + 0)*16 + lrow], Sp = sMS[(wp*2 + 1)*16 + lrow];
    float Mf = fmaxf(M, Mp);
    float Sf = S*expf(M - Mf) + Sp*expf(Mp - Mf);
    float fac = expf(M - Mf) / Sf;

    if (g == 1) {
        #pragma unroll
        for (int dt = 0; dt < 4; ++dt)
        #pragma unroll
        for (int r = 0; r < 4; ++r) {
            int d = dt*16 + lg*4 + r;
            sAccR[(qw*64 + d)*16 + lrow] = (o1[dt][r] - o2[dt][r]) * fac;
            sAccI[(qw*64 + d)*16 + lrow] = o3[dt][r] * fac;
        }
    }
    __syncthreads();
    if (g == 0) {
        #pragma unroll
        for (int dt = 0; dt < 4; ++dt)
        #pragma unroll
        for (int r = 0; r < 4; ++r) {
            int d = dt*16 + lg*4 + r;
            sAccR[(qw*64 + d)*16 + lrow] += (o1[dt][r] - o2[dt][r]) * fac;
            sAccI[(qw*64 + d)*16 + lrow] += o3[dt][r] * fac;
        }
    }
    __syncthreads();
    // coalesced bf16 write-out: 512 thr, thread -> (row = tid>>3, d0 = (tid&7)*8)
    {
        int row = tid >> 3, d0 = (tid & 7) * 8;
        int qb = row >> 4, qr = row & 15;
        unsigned int pr[4], pi[4];
        #pragma unroll
        for (int jj = 0; jj < 4; ++jj) {
            float r0 = sAccR[(qb*64 + d0 + 2*jj + 0)*16 + qr];
            float r1 = sAccR[(qb*64 + d0 + 2*jj + 1)*16 + qr];
            float i0 = sAccI[(qb*64 + d0 + 2*jj + 0)*16 + qr];
            float i1 = sAccI[(qb*64 + d0 + 2*jj + 1)*16 + qr];
            pr[jj] = (unsigned int)f2bf(r0) | ((unsigned int)f2bf(r1) << 16);
            pi[jj] = (unsigned int)f2bf(i0) | ((unsigned int)f2bf(i1) << 16);
        }
        int b = bh >> 3, h = bh & 7;
        size_t off = (((size_t)(b*SEQ + qt*64 + row)) << 9) + h*64 + d0;
        *(uint4*)(aor + off) = make_uint4(pr[0], pr[1], pr[2], pr[3]);
        *(uint4*)(aoi + off) = make_uint4(pi[0], pi[1], pi[2], pi[3]);
    }
}

// ---------------- launch ----------------
extern "C" void kernel_launch(void* const* d_in, const int* in_sizes, int n_in,
                              void* d_out, int out_size, void* d_ws, size_t ws_size,
                              hipStream_t stream)
{
    const float* x_real  = (const float*)d_in[0];
    const float* x_imag  = (const float*)d_in[1];
    const float* ln1_g_r = (const float*)d_in[2];
    const float* ln1_b_r = (const float*)d_in[3];
    const float* ln1_g_i = (const float*)d_in[4];
    const float* ln1_b_i = (const float*)d_in[5];
    const float* ln2_g_r = (const float*)d_in[6];
    const float* ln2_b_r = (const float*)d_in[7];
    const float* ln2_g_i = (const float*)d_in[8];
    const float* ln2_b_i = (const float*)d_in[9];
    const float* qkv_w_r = (const float*)d_in[10];
    const float* qkv_w_i = (const float*)d_in[11];
    const float* out_w_r = (const float*)d_in[12];
    const float* out_w_i = (const float*)d_in[13];
    const float* out_b_r = (const float*)d_in[14];
    const float* out_b_i = (const float*)d_in[15];
    const float* ff_w_r  = (const float*)d_in[16];
    const float* ff_w_i  = (const float*)d_in[17];
    const float* stepp   = (const float*)d_in[18];
    const float* lamb    = (const float*)d_in[19];

    const size_t SZ = (size_t)ROWS * DIM;       // 1M elems
    const size_t WSEG = (size_t)DIM * DIM;      // 256K elems
    float* xr = (float*)d_ws;
    float* xi = xr + SZ;
    unsigned short* xnr = (unsigned short*)(xi + SZ);
    unsigned short* xni = xnr + SZ;
    unsigned short* whr = xni + SZ;
    unsigned short* whi = whr + SZ;
    unsigned short* aor = whi + SZ;
    unsigned short* aoi = aor + SZ;
    unsigned short* wb  = aoi + SZ;             // 6*WSEG bf16 (one layer)

    float* outR = (float*)d_out;
    float* outI = outR + SZ;

    hipMemcpyAsync(xr, x_real, SZ*sizeof(float), hipMemcpyDeviceToDevice, stream);
    hipMemcpyAsync(xi, x_imag, SZ*sizeof(float), hipMemcpyDeviceToDevice, stream);

    for (int l = 0; l < DEPTHL; ++l) {
        const size_t WO = (size_t)l * WSEG;
        convw<<<1536, 256, 0, stream>>>(qkv_w_r + WO, qkv_w_i + WO, out_w_r + WO,
                                        out_w_i + WO, ff_w_r + WO, ff_w_i + WO, wb);
        ln_kernel<<<ROWS, 256, 0, stream>>>(xr, xi,
            ln1_g_r + l*DIM, ln1_b_r + l*DIM, ln1_g_i + l*DIM, ln1_b_i + l*DIM, xnr, xni);
        cgemm_mfma<0><<<dim3(64, 8), 256, 0, stream>>>(xnr, xni, wb, wb + WSEG,
            whr, whi, nullptr, nullptr, nullptr, nullptr, nullptr, nullptr, l);
        attn_mfma<<<dim3(32, 8), 512, 0, stream>>>(whr, whi, aor, aoi);
        cgemm_mfma<1><<<dim3(64, 8), 256, 0, stream>>>(aor, aoi, wb + 2*WSEG, wb + 3*WSEG,
            nullptr, nullptr, xr, xi, out_b_r + l*DIM, out_b_i + l*DIM, nullptr, nullptr, l);
        ln_kernel<<<ROWS, 256, 0, stream>>>(xr, xi,
            ln2_g_r + l*DIM, ln2_b_r + l*DIM, ln2_g_i + l*DIM, ln2_b_i + l*DIM, xnr, xni);
        float* dstR = (l == DEPTHL-1) ? outR : xr;
        float* dstI = (l == DEPTHL-1) ? outI : xi;
        cgemm_mfma<2><<<dim3(64, 8), 256, 0, stream>>>(xnr, xni, wb + 4*WSEG, wb + 5*WSEG,
            nullptr, nullptr, dstR, dstI, nullptr, nullptr, stepp, lamb, l);
    }
}